// Round 9
// baseline (211.870 us; speedup 1.0000x reference)
//
#include <hip/hip_runtime.h>
#include <stdint.h>

#define N      8192
#define KDIM   256
#define BM     128
#define TILES  (N / BM)                    // 64
#define NPAIRS (TILES * (TILES + 1) / 2)   // 2080
#define MARGIN 0.5f
#define PLANE_Q ((size_t)N * 64)           // one quarter-K plane of Xq (512 KB)

typedef float     f32x4 __attribute__((ext_vector_type(4)));
typedef long long i64x2 __attribute__((ext_vector_type(2)));

// async global->LDS, 16 B/lane; LDS dest = wave-uniform base + lane*16
__device__ __forceinline__ void async_copy16(const void* g, void* l) {
    __builtin_amdgcn_global_load_lds(
        (__attribute__((address_space(1))) void*)(g),
        (__attribute__((address_space(3))) void*)(l),
        16, 0, 0);
}

#if !__has_builtin(__builtin_amdgcn_cvt_pk_fp8_f32)
// manual fp32 -> e4m3fn RNE fallback
__device__ __forceinline__ uint32_t f2e4m3(float f) {
    uint32_t u = __float_as_uint(f);
    uint32_t s = (u >> 24) & 0x80u;
    uint32_t au = u & 0x7fffffffu;
    if (au == 0) return s;
    int32_t  exp = (int32_t)(au >> 23) - 127;
    uint32_t man = (au & 0x7fffffu) | 0x800000u;
    uint32_t code;
    if (exp >= -6) {
        code = (uint32_t)((exp + 7) << 3) | ((man >> 20) & 7u);
        uint32_t rem = man & 0xFFFFFu;
        if (rem > 0x80000u || (rem == 0x80000u && (code & 1u))) code++;
    } else {
        int shift = 14 - exp;
        if (shift > 24) return s;
        code = man >> shift;
        uint32_t rem = man & ((1u << shift) - 1u);
        uint32_t h = 1u << (shift - 1);
        if (rem > h || (rem == h && (code & 1u))) code++;
    }
    return s | code;
}
__device__ __forceinline__ uint32_t pack_fp8x4(float4 v) {
    return f2e4m3(v.x) | (f2e4m3(v.y) << 8) | (f2e4m3(v.z) << 16) |
           (f2e4m3(v.w) << 24);
}
#else
__device__ __forceinline__ uint32_t pack_fp8x4(float4 v) {
    int pk = __builtin_amdgcn_cvt_pk_fp8_f32(v.x, v.y, 0, false);
    pk = __builtin_amdgcn_cvt_pk_fp8_f32(v.z, v.w, pk, true);
    return (uint32_t)pk;
}
#endif

// ---------------------------------------------------------------------------
// Prepass: fp32 -> fp8 e4m3 into FOUR quarter-K planes (validated r6 layout).
// Within a quarter-row (64 B): byte = chunk*16 + kstep*8 + b. One 16 B
// granule per (row, chunk) feeds both k-steps of one lane's MFMA operand
// (i64x2 .x/.y); LDS granule index == frow -> conflict-free ds_read_b128.
// Packs per-row metadata {sq_bits, tgt} (8 B).
// ---------------------------------------------------------------------------
__global__ __launch_bounds__(256) void prep_kernel(
        const float* __restrict__ X, const int* __restrict__ tgt,
        uint8_t* __restrict__ Xq, uint2* __restrict__ metaG) {
    int row  = blockIdx.x * 4 + (threadIdx.x >> 6);
    int lane = threadIdx.x & 63;

    float4 v = *((const float4*)(X + (size_t)row * KDIM) + lane);
    float ss = v.x * v.x + v.y * v.y + v.z * v.z + v.w * v.w;
    uint32_t pk = pack_fp8x4(v);

    int k0 = lane * 4;            // global k of first element
    int u  = k0 >> 6;             // quarter-K plane
    int rem = k0 & 63;
    int ks  = rem >> 5;           // k-step within unit (0/1)
    int ch  = (rem >> 3) & 3;     // 8-elem chunk (fquad) within k-step
    size_t off = (size_t)u * PLANE_Q + (size_t)row * 64
               + ch * 16 + ks * 8 + (k0 & 7);
    *(uint32_t*)(Xq + off) = pk;

    #pragma unroll
    for (int o = 32; o > 0; o >>= 1) ss += __shfl_down(ss, o, 64);
    if (lane == 0)
        metaG[row] = make_uint2(__float_as_uint(ss), (uint32_t)tgt[row]);
}

// ---------------------------------------------------------------------------
// Compute one K=64 unit: 4 a-frags + 4 b-frags (ds_read_b128, conflict-free),
// 32 MFMAs.
// ---------------------------------------------------------------------------
__device__ __forceinline__ void compute_unit(
        const uint8_t* Au, const uint8_t* Bu, int wm4, int wn4, int fragOff,
        f32x4 (&acc)[4][4]) {
    i64x2 a2[4], b2[4];
    #pragma unroll
    for (int im = 0; im < 4; ++im)
        a2[im] = *(const i64x2*)(Au + (size_t)(wm4 + im) * 1024 + fragOff);
    #pragma unroll
    for (int in = 0; in < 4; ++in)
        b2[in] = *(const i64x2*)(Bu + (size_t)(wn4 + in) * 1024 + fragOff);
    #pragma unroll
    for (int im = 0; im < 4; ++im)
        #pragma unroll
        for (int in = 0; in < 4; ++in)
            acc[im][in] = __builtin_amdgcn_mfma_f32_16x16x32_fp8_fp8(
                a2[im].x, b2[in].x, acc[im][in], 0, 0, 0);
    #pragma unroll
    for (int im = 0; im < 4; ++im)
        #pragma unroll
        for (int in = 0; in < 4; ++in)
            acc[im][in] = __builtin_amdgcn_mfma_f32_16x16x32_fp8_fp8(
                a2[im].y, b2[in].y, acc[im][in], 0, 0, 0);
}

// issue one unit's staging: per wave rowblks {2w,2w+1} of A and B (4 instr)
__device__ __forceinline__ void stage_unit(
        const uint8_t* gA, const uint8_t* gB,
        uint8_t* lA, uint8_t* lB, int wave) {
    size_t o0 = (size_t)(2 * wave) * 1024, o1 = o0 + 1024;
    async_copy16(gA + o0, lA + o0);
    async_copy16(gA + o1, lA + o1);
    async_copy16(gB + o0, lB + o0);
    async_copy16(gB + o1, lB + o1);
}

#define WAITV0() asm volatile("s_waitcnt vmcnt(0)" ::: "memory")
#define SBAR()   do { __builtin_amdgcn_sched_barrier(0);                 \
                      __builtin_amdgcn_s_barrier();                      \
                      __builtin_amdgcn_sched_barrier(0); } while (0)

// ---------------------------------------------------------------------------
// Main: triangular grid of 128x128 Gram tiles, fp8 MFMA. SINGLE-buffered
// K=64 unit staging: LDS = 8KB(A) + 8KB(B) + 2KB(meta) ~= 18.5 KB ->
// 8 blocks/CU = 32 waves/CU (2x the occupancy of every prior variant).
// Rationale (r7 counters): all pipes <15% busy, occ 30% -> TLP-starved
// latency-bound; sync cost is covered by resident-block overlap (r6 proved
// counted-vmcnt gains nothing at 4 blocks/CU). Simple per-unit schedule:
// stage -> vmcnt(0)+barrier -> compute -> barrier. Fused loss epilogue.
// ---------------------------------------------------------------------------
__global__ __launch_bounds__(256, 8) void loss_kernel(
        const uint8_t* __restrict__ Xq, const uint2* __restrict__ metaG,
        float* __restrict__ partials) {
    // ---- triangular decode: p -> (bi, bj), bi <= bj ----
    const int p = blockIdx.x;
    float tf = 2.0f * TILES + 1.0f;
    int bi = (int)((tf - sqrtf(tf * tf - 8.0f * (float)p)) * 0.5f);
    if (bi < 0) bi = 0;
    while (bi > 0 && (bi * TILES - bi * (bi - 1) / 2) > p) --bi;
    while (((bi + 1) * TILES - (bi + 1) * bi / 2) <= p) ++bi;
    const int bj = bi + (p - (bi * TILES - bi * (bi - 1) / 2));

    __shared__ __align__(16) uint8_t As[8192];      // 8 KB (one K=64 unit)
    __shared__ __align__(16) uint8_t Bs[8192];      // 8 KB
    __shared__ __align__(16) uint2   mA[BM], mB[BM];  // {sq,tgt} 2 KB
    __shared__ float wsum[4];

    const int tid  = threadIdx.x;
    const int wave = tid >> 6;
    const int lane = tid & 63;

    const int frow  = lane & 15;
    const int fquad = lane >> 4;
    const int wm4 = (wave >> 1) * 4;       // A rowblk base (rows wm=wm4*16)
    const int wn4 = (wave & 1) * 4;        // B rowblk base
    const int fragOff = fquad * 256 + frow * 16;

    // per-lane global source offset: granule (chunk=lane>>4) of row (lane&15)
    const size_t srcLane = (size_t)(lane & 15) * 64 + (size_t)(lane >> 4) * 16;
    const uint8_t* gA = Xq + (size_t)bi * BM * 64 + srcLane;
    const uint8_t* gB = Xq + (size_t)bj * BM * 64 + srcLane;

    // ---- issue metadata + unit 0 ----
    async_copy16((const uint8_t*)(metaG + bi * BM) + (size_t)lane * 16, mA);
    async_copy16((const uint8_t*)(metaG + bj * BM) + (size_t)lane * 16, mB);
    stage_unit(gA, gB, As, Bs, wave);

    f32x4 acc[4][4];
    #pragma unroll
    for (int im = 0; im < 4; ++im)
        #pragma unroll
        for (int in = 0; in < 4; ++in)
            acc[im][in] = (f32x4){0.f, 0.f, 0.f, 0.f};

    #pragma unroll
    for (int u = 0; u < 4; ++u) {
        WAITV0(); SBAR();                  // unit u (and meta) in LDS
        compute_unit(As, Bs, wm4, wn4, fragOff, acc);
        if (u < 3) {
            SBAR();                        // all waves done reading unit u
            stage_unit(gA + (size_t)(u + 1) * PLANE_Q,
                       gB + (size_t)(u + 1) * PLANE_Q, As, Bs, wave);
        }
    }

    // ---- epilogue: C/D map col=lane&15, row=(lane>>4)*4+reg ----
    const int wm = wm4 * 16, wn = wn4 * 16;
    uint2 mb[4];
    #pragma unroll
    for (int in = 0; in < 4; ++in) mb[in] = mB[wn + in * 16 + frow];

    float lsum = 0.0f;
    if (bi != bj) {
        #pragma unroll
        for (int im = 0; im < 4; ++im) {
            #pragma unroll
            for (int r = 0; r < 4; ++r) {
                uint2 ma = mA[wm + im * 16 + fquad * 4 + r];
                #pragma unroll
                for (int in = 0; in < 4; ++in) {
                    float d = fmaf(-2.0f, acc[im][in][r],
                                   __uint_as_float(ma.x) + __uint_as_float(mb[in].x));
                    lsum += (ma.y == mb[in].y) ? d : fmaxf(MARGIN - d, 0.0f);
                }
            }
        }
        lsum *= 2.0f;   // (i,j) and (j,i)
    } else {
        #pragma unroll
        for (int im = 0; im < 4; ++im) {
            #pragma unroll
            for (int r = 0; r < 4; ++r) {
                int rl = wm + im * 16 + fquad * 4 + r;
                uint2 ma = mA[rl];
                #pragma unroll
                for (int in = 0; in < 4; ++in) {
                    int cl = wn + in * 16 + frow;
                    float d = fmaf(-2.0f, acc[im][in][r],
                                   __uint_as_float(ma.x) + __uint_as_float(mb[in].x));
                    float c = (ma.y == mb[in].y) ? d : fmaxf(MARGIN - d, 0.0f);
                    float w = (rl < cl) ? 2.0f : ((rl == cl) ? 1.0f : 0.0f);
                    lsum += w * c;
                }
            }
        }
    }

    #pragma unroll
    for (int o = 32; o > 0; o >>= 1) lsum += __shfl_down(lsum, o, 64);
    if (lane == 0) wsum[wave] = lsum;
    __syncthreads();
    if (tid == 0) partials[p] = wsum[0] + wsum[1] + wsum[2] + wsum[3];
}

// ---------------------------------------------------------------------------
// Final deterministic reduce of NPAIRS partials -> scaled scalar.
// ---------------------------------------------------------------------------
__global__ __launch_bounds__(256) void reduce_kernel(
        const float* __restrict__ partials, float* __restrict__ out,
        int n, float scale) {
    float s = 0.0f;
    for (int i = threadIdx.x; i < n; i += 256) s += partials[i];
    __shared__ float w[4];
    #pragma unroll
    for (int o = 32; o > 0; o >>= 1) s += __shfl_down(s, o, 64);
    int wave = threadIdx.x >> 6, lane = threadIdx.x & 63;
    if (lane == 0) w[wave] = s;
    __syncthreads();
    if (threadIdx.x == 0) out[0] = (w[0] + w[1] + w[2] + w[3]) * scale;
}

extern "C" void kernel_launch(void* const* d_in, const int* in_sizes, int n_in,
                              void* d_out, int out_size, void* d_ws, size_t ws_size,
                              hipStream_t stream) {
    (void)in_sizes; (void)n_in; (void)out_size; (void)ws_size;
    const float* X   = (const float*)d_in[0];
    const int*   tgt = (const int*)d_in[1];

    uint8_t* Xq       = (uint8_t*)d_ws;                              // 2 MB (4 planes)
    uint2*   metaG    = (uint2*)((char*)d_ws + 4 * PLANE_Q);         // 64 KB
    float*   partials = (float*)((char*)metaG + (size_t)N * 8);      // NPAIRS

    prep_kernel<<<N / 4, 256, 0, stream>>>(X, tgt, Xq, metaG);
    loss_kernel<<<NPAIRS, 256, 0, stream>>>(Xq, metaG, partials);

    const float scale = (float)(1.0 / ((double)N * ((double)N - 1.0) * 2.0));
    reduce_kernel<<<1, 256, 0, stream>>>(partials, (float*)d_out, NPAIRS, scale);
}

// Round 11
// 79.729 us; speedup vs baseline: 2.6574x; 2.6574x over previous
//
#include <hip/hip_runtime.h>
#include <stdint.h>

#define N      8192
#define KDIM   256
#define BM     128
#define TILES  (N / BM)                    // 64
#define NPAIRS (TILES * (TILES + 1) / 2)   // 2080
#define MARGIN 0.5f

typedef float     f32x4 __attribute__((ext_vector_type(4)));
typedef long long i64x2 __attribute__((ext_vector_type(2)));

// async global->LDS, 16 B/lane; LDS dest = wave-uniform base + lane*16
__device__ __forceinline__ void async_copy16(const void* g, void* l) {
    __builtin_amdgcn_global_load_lds(
        (__attribute__((address_space(1))) void*)(g),
        (__attribute__((address_space(3))) void*)(l),
        16, 0, 0);
}

#if !__has_builtin(__builtin_amdgcn_cvt_pk_fp8_f32)
// manual fp32 -> e4m3fn RNE fallback
__device__ __forceinline__ uint32_t f2e4m3(float f) {
    uint32_t u = __float_as_uint(f);
    uint32_t s = (u >> 24) & 0x80u;
    uint32_t au = u & 0x7fffffffu;
    if (au == 0) return s;
    int32_t  exp = (int32_t)(au >> 23) - 127;
    uint32_t man = (au & 0x7fffffu) | 0x800000u;
    uint32_t code;
    if (exp >= -6) {
        code = (uint32_t)((exp + 7) << 3) | ((man >> 20) & 7u);
        uint32_t rem = man & 0xFFFFFu;
        if (rem > 0x80000u || (rem == 0x80000u && (code & 1u))) code++;
    } else {
        int shift = 14 - exp;
        if (shift > 24) return s;
        code = man >> shift;
        uint32_t rem = man & ((1u << shift) - 1u);
        uint32_t h = 1u << (shift - 1);
        if (rem > h || (rem == h && (code & 1u))) code++;
    }
    return s | code;
}
__device__ __forceinline__ uint32_t pack_fp8x4(float4 v) {
    return f2e4m3(v.x) | (f2e4m3(v.y) << 8) | (f2e4m3(v.z) << 16) |
           (f2e4m3(v.w) << 24);
}
#else
__device__ __forceinline__ uint32_t pack_fp8x4(float4 v) {
    int pk = __builtin_amdgcn_cvt_pk_fp8_f32(v.x, v.y, 0, false);
    pk = __builtin_amdgcn_cvt_pk_fp8_f32(v.z, v.w, pk, true);
    return (uint32_t)pk;
}
#endif

// ---------------------------------------------------------------------------
// Prepass (VALIDATED 80.7us baseline layout): fp32 -> fp8 e4m3, stored in
// the loss kernel's LDS-ready layout: row = [half0 128B][half1 128B]; each
// half = 8 16B slots; slot index (fquad*2 + ks2) ^ (row&7); slot =
// {chunk ks even (8B), chunk ks odd (8B)}. Exact fp32 row norms.
// ---------------------------------------------------------------------------
__global__ __launch_bounds__(256) void prep_kernel(
        const float* __restrict__ X, uint8_t* __restrict__ Xq,
        float* __restrict__ sq) {
    int row  = blockIdx.x * 4 + (threadIdx.x >> 6);
    int lane = threadIdx.x & 63;

    float4 v = *((const float4*)(X + (size_t)row * KDIM) + lane);
    float ss = v.x * v.x + v.y * v.y + v.z * v.z + v.w * v.w;
    uint32_t pk = pack_fp8x4(v);

    int kg = lane * 4;            // global k of first element
    int h  = kg >> 7;             // K-half
    int kh = kg & 127;
    int ks = kh >> 5;             // k-step within half (0..3)
    int fq = (kh >> 3) & 3;       // fquad owning this chunk
    int slot = (fq * 2 + (ks >> 1)) ^ (row & 7);
    size_t off = (size_t)row * 256 + h * 128 + slot * 16 + (ks & 1) * 8 + (kh & 4);
    *(uint32_t*)(Xq + off) = pk;

    #pragma unroll
    for (int o = 32; o > 0; o >>= 1) ss += __shfl_down(ss, o, 64);
    if (lane == 0) sq[row] = ss;
}

// ---------------------------------------------------------------------------
// Main (champion structure, unchanged): triangular grid of 128x128 Gram
// tiles, fp8 MFMA. BK=128 halves, LDS 32KB+meta -> 4 blocks/CU. Swizzled
// ds_read_b128 fragments. ONLY change vs the 80.7us baseline: epilogue
// metadata hoisted into registers (validated form from r7/r8).
// ---------------------------------------------------------------------------
__global__ __launch_bounds__(256, 4) void loss_kernel(
        const uint8_t* __restrict__ Xq, const float* __restrict__ sq,
        const int* __restrict__ tgt, float* __restrict__ partials) {
    // ---- triangular decode: p -> (bi, bj), bi <= bj ----
    const int p = blockIdx.x;
    float tf = 2.0f * TILES + 1.0f;
    int bi = (int)((tf - sqrtf(tf * tf - 8.0f * (float)p)) * 0.5f);
    if (bi < 0) bi = 0;
    while (bi > 0 && (bi * TILES - bi * (bi - 1) / 2) > p) --bi;
    while (((bi + 1) * TILES - (bi + 1) * bi / 2) <= p) ++bi;
    const int bj = bi + (p - (bi * TILES - bi * (bi - 1) / 2));

    __shared__ __align__(16) uint8_t As[BM * 128];   // 16 KB (one K-half)
    __shared__ __align__(16) uint8_t Bs[BM * 128];   // 16 KB
    __shared__ float sqa_s[BM], sqb_s[BM];
    __shared__ int   ta_s[BM],  tb_s[BM];
    __shared__ float wsum[4];

    const int tid  = threadIdx.x;
    const int wave = tid >> 6;
    const int lane = tid & 63;

    if (tid < 128) {
        sqa_s[tid] = sq[bi * BM + tid];
        ta_s[tid]  = tgt[bi * BM + tid];
    } else {
        int r = tid - 128;
        sqb_s[r] = sq[bj * BM + r];
        tb_s[r]  = tgt[bj * BM + r];
    }

    // staging lane decomposition: 8 rows x 8 slots(16B) per instruction
    const int lrow = lane >> 3;            // row within 8-row group
    const int lb   = (lane & 7) * 16;      // byte within 128B half-row
    const uint8_t* gA0 = Xq + ((size_t)bi * BM + wave * 32 + lrow) * 256 + lb;
    const uint8_t* gB0 = Xq + ((size_t)bj * BM + wave * 32 + lrow) * 256 + lb;
    uint8_t* lA = As + wave * 32 * 128;    // wave-uniform LDS bases
    uint8_t* lB = Bs + wave * 32 * 128;

    const int frow  = lane & 15;
    const int fquad = lane >> 4;
    const int wm = (wave >> 1) * 64;
    const int wn = (wave & 1) * 64;
    const int key = frow & 7;
    const uint8_t* aB = As + (wm + frow) * 128;
    const uint8_t* bB = Bs + (wn + frow) * 128;

    f32x4 acc[4][4];
    #pragma unroll
    for (int im = 0; im < 4; ++im)
        #pragma unroll
        for (int in = 0; in < 4; ++in)
            acc[im][in] = (f32x4){0.f, 0.f, 0.f, 0.f};

    #pragma unroll
    for (int h = 0; h < 2; ++h) {
        // stage K-half h (A: 16KB, B: 16KB across 4 waves)
        #pragma unroll
        for (int q = 0; q < 4; ++q) {
            async_copy16(gA0 + h * 128 + q * 8 * 256, lA + q * 1024);
            async_copy16(gB0 + h * 128 + q * 8 * 256, lB + q * 1024);
        }
        __syncthreads();

        #pragma unroll
        for (int ks2 = 0; ks2 < 2; ++ks2) {
            const int t = ((fquad * 2 + ks2) ^ key) * 16;
            i64x2 a2[4], b2[4];
            #pragma unroll
            for (int im = 0; im < 4; ++im)
                a2[im] = *(const i64x2*)(aB + im * 16 * 128 + t);
            #pragma unroll
            for (int in = 0; in < 4; ++in)
                b2[in] = *(const i64x2*)(bB + in * 16 * 128 + t);
            #pragma unroll
            for (int im = 0; im < 4; ++im)
                #pragma unroll
                for (int in = 0; in < 4; ++in)
                    acc[im][in] = __builtin_amdgcn_mfma_f32_16x16x32_fp8_fp8(
                        a2[im].x, b2[in].x, acc[im][in], 0, 0, 0);
            #pragma unroll
            for (int im = 0; im < 4; ++im)
                #pragma unroll
                for (int in = 0; in < 4; ++in)
                    acc[im][in] = __builtin_amdgcn_mfma_f32_16x16x32_fp8_fp8(
                        a2[im].y, b2[in].y, acc[im][in], 0, 0, 0);
        }
        if (h == 0) __syncthreads();   // LDS reuse guard before restaging
    }

    // ---- epilogue: C/D map col=lane&15, row=(lane>>4)*4+reg ----
    // metadata hoisted to registers (r7/r8-validated form)
    float sqb_r[4]; int tb_r[4];
    #pragma unroll
    for (int in = 0; in < 4; ++in) {
        sqb_r[in] = sqb_s[wn + in * 16 + frow];
        tb_r[in]  = tb_s[wn + in * 16 + frow];
    }

    float lsum = 0.0f;
    if (bi != bj) {
        #pragma unroll
        for (int im = 0; im < 4; ++im) {
            #pragma unroll
            for (int r = 0; r < 4; ++r) {
                int rl = wm + im * 16 + fquad * 4 + r;
                float sqa = sqa_s[rl]; int ta = ta_s[rl];
                #pragma unroll
                for (int in = 0; in < 4; ++in) {
                    float d = fmaf(-2.0f, acc[im][in][r], sqa + sqb_r[in]);
                    lsum += (ta == tb_r[in]) ? d : fmaxf(MARGIN - d, 0.0f);
                }
            }
        }
        lsum *= 2.0f;   // (i,j) and (j,i)
    } else {
        #pragma unroll
        for (int im = 0; im < 4; ++im) {
            #pragma unroll
            for (int r = 0; r < 4; ++r) {
                int rl = wm + im * 16 + fquad * 4 + r;
                float sqa = sqa_s[rl]; int ta = ta_s[rl];
                #pragma unroll
                for (int in = 0; in < 4; ++in) {
                    int cl = wn + in * 16 + frow;
                    float d = fmaf(-2.0f, acc[im][in][r], sqa + sqb_r[in]);
                    float c = (ta == tb_r[in]) ? d : fmaxf(MARGIN - d, 0.0f);
                    float w = (rl < cl) ? 2.0f : ((rl == cl) ? 1.0f : 0.0f);
                    lsum += w * c;
                }
            }
        }
    }

    #pragma unroll
    for (int o = 32; o > 0; o >>= 1) lsum += __shfl_down(lsum, o, 64);
    if (lane == 0) wsum[wave] = lsum;
    __syncthreads();
    if (tid == 0) partials[p] = wsum[0] + wsum[1] + wsum[2] + wsum[3];
}

// ---------------------------------------------------------------------------
// Final deterministic reduce of NPAIRS partials -> scaled scalar.
// ---------------------------------------------------------------------------
__global__ __launch_bounds__(256) void reduce_kernel(
        const float* __restrict__ partials, float* __restrict__ out,
        int n, float scale) {
    float s = 0.0f;
    for (int i = threadIdx.x; i < n; i += 256) s += partials[i];
    __shared__ float w[4];
    #pragma unroll
    for (int o = 32; o > 0; o >>= 1) s += __shfl_down(s, o, 64);
    int wave = threadIdx.x >> 6, lane = threadIdx.x & 63;
    if (lane == 0) w[wave] = s;
    __syncthreads();
    if (threadIdx.x == 0) out[0] = (w[0] + w[1] + w[2] + w[3]) * scale;
}

extern "C" void kernel_launch(void* const* d_in, const int* in_sizes, int n_in,
                              void* d_out, int out_size, void* d_ws, size_t ws_size,
                              hipStream_t stream) {
    (void)in_sizes; (void)n_in; (void)out_size; (void)ws_size;
    const float* X   = (const float*)d_in[0];
    const int*   tgt = (const int*)d_in[1];

    uint8_t* Xq     = (uint8_t*)d_ws;                              // 2 MB fp8
    float* sq       = (float*)((char*)d_ws + (size_t)N * KDIM);
    float* partials = sq + N;                                      // NPAIRS

    prep_kernel<<<N / 4, 256, 0, stream>>>(X, Xq, sq);
    loss_kernel<<<NPAIRS, 256, 0, stream>>>(Xq, sq, tgt, partials);

    const float scale = (float)(1.0 / ((double)N * ((double)N - 1.0) * 2.0));
    reduce_kernel<<<1, 256, 0, stream>>>(partials, (float*)d_out, NPAIRS, scale);
}